// Round 15
// baseline (3930.053 us; speedup 1.0000x reference)
//
#include <hip/hip_runtime.h>
#include <hip/hip_bf16.h>

typedef __attribute__((ext_vector_type(8))) short s16x8;
typedef __attribute__((ext_vector_type(4))) float f32x4;

__device__ inline unsigned short f2bf(float f) {
  unsigned u = __builtin_bit_cast(unsigned, f);
  unsigned r = (u + 0x7FFFu + ((u >> 16) & 1u)) >> 16;  // RTNE
  return (unsigned short)r;
}
__device__ inline float bf2f(short v) {
  return __builtin_bit_cast(float, ((unsigned)(unsigned short)v) << 16);
}
__device__ inline float bflo(unsigned w) { return __builtin_bit_cast(float, w << 16); }
__device__ inline float bfhi(unsigned w) { return __builtin_bit_cast(float, w & 0xFFFF0000u); }
__device__ inline float sigf(float x) { return 1.f / (1.f + __expf(-x)); }
__device__ inline float tanhf_(float x) { float e = __expf(2.f * x); return 1.f - 2.f / (e + 1.f); }

// ---------------------------------------------------------------- packers (R13-identical streams)
__global__ void packT(const float* __restrict__ src, unsigned* __restrict__ dst,
                      int rows, int scols, int kkPairs) {
  int i = blockIdx.x * 256 + threadIdx.x;
  if (i >= kkPairs * rows) return;
  int kk = i / rows, o = i % rows;
  int k0 = 2 * kk, k1 = 2 * kk + 1;
  float lo = (k0 < scols) ? src[(size_t)o * scols + k0] : 0.f;
  float hi = (k1 < scols) ? src[(size_t)o * scols + k1] : 0.f;
  dst[i] = (unsigned)f2bf(lo) | ((unsigned)f2bf(hi) << 16);
}
__global__ void packTg(const float* __restrict__ src, unsigned* __restrict__ dst,
                       int scols, int kkPairs) {
  int i = blockIdx.x * 256 + threadIdx.x;
  if (i >= kkPairs * 512) return;
  int kk = i / 512, j = i % 512;
  int row = (j & 3) * 128 + (j >> 2);
  int k0 = 2 * kk, k1 = 2 * kk + 1;
  float lo = (k0 < scols) ? src[(size_t)row * scols + k0] : 0.f;
  float hi = (k1 < scols) ? src[(size_t)row * scols + k1] : 0.f;
  dst[i] = (unsigned)f2bf(lo) | ((unsigned)f2bf(hi) << 16);
}
__global__ void f2bf_vec(const float* __restrict__ src, unsigned short* __restrict__ dst) {
  size_t i = ((size_t)blockIdx.x * 256 + threadIdx.x) * 4;
  float4 v = *(const float4*)(src + i);
  ushort4 o;
  o.x = f2bf(v.x); o.y = f2bf(v.y); o.z = f2bf(v.z); o.w = f2bf(v.w);
  *(ushort4*)(dst + i) = o;
}
// fold lin_c into Wo:  lwcWo[o4][k] = sum_j linW[o4][128+j]*Wo[j][k];  linb2 = linb + linW_c . bo
__global__ void foldWo(const float* __restrict__ linW, const float* __restrict__ Wo,
                       const float* __restrict__ bo, const float* __restrict__ linb,
                       float* __restrict__ lwcWo, float* __restrict__ linb2) {
  const int tid = threadIdx.x;              // 512
  const int o4 = tid >> 7, k = tid & 127;
  float acc = 0.f;
  for (int j = 0; j < 128; ++j) acc += linW[o4 * 256 + 128 + j] * Wo[(size_t)j * 128 + k];
  lwcWo[o4 * 128 + k] = acc;
  if (k == 0) {
    float a2 = linb[o4];
    for (int j = 0; j < 128; ++j) a2 += linW[o4 * 256 + 128 + j] * bo[j];
    linb2[o4] = a2;
  }
}

// ---------------------------------------------------------------- GEMM C = A @ B^T + bias
#define BM 128
#define BN 128
#define BKK 32

template<int A_BF16, int C_BF16>
__global__ __launch_bounds__(256) void gemm_bt(const void* __restrict__ Av,
    const float* __restrict__ B, const float* __restrict__ bias,
    void* __restrict__ Cv, int M, int N, int K) {
  __shared__ short sA[BM * BKK];
  __shared__ short sB[BN * BKK];
  const int tid = threadIdx.x;
  const int l = tid & 63;
  const int wid = tid >> 6;
  const int wr = wid >> 1, wc = wid & 1;
  const int lr = l & 15, kg = l >> 4;
  const int bn = blockIdx.x, bm = blockIdx.y;
  const int arow = tid >> 1;
  const int acol = (tid & 1) * 16;

  f32x4 acc[4][4];
#pragma unroll
  for (int i = 0; i < 4; ++i)
#pragma unroll
    for (int j = 0; j < 4; ++j) acc[i][j] = (f32x4){0.f, 0.f, 0.f, 0.f};

  for (int kt = 0; kt < K; kt += BKK) {
    __syncthreads();
    if (A_BF16) {
      const unsigned short* src = (const unsigned short*)Av + (size_t)(bm * BM + arow) * K + kt + acol;
      *(s16x8*)&sA[arow * BKK + acol] = *(const s16x8*)src;
      *(s16x8*)&sA[arow * BKK + acol + 8] = *(const s16x8*)(src + 8);
    } else {
      const float* src = (const float*)Av + (size_t)(bm * BM + arow) * K + kt + acol;
      s16x8 v0, v1;
#pragma unroll
      for (int e = 0; e < 8; ++e) { v0[e] = (short)f2bf(src[e]); v1[e] = (short)f2bf(src[8 + e]); }
      *(s16x8*)&sA[arow * BKK + acol] = v0;
      *(s16x8*)&sA[arow * BKK + acol + 8] = v1;
    }
    {
      const float* src = B + (size_t)(bn * BN + arow) * K + kt + acol;
      s16x8 v0, v1;
#pragma unroll
      for (int e = 0; e < 8; ++e) { v0[e] = (short)f2bf(src[e]); v1[e] = (short)f2bf(src[8 + e]); }
      *(s16x8*)&sB[arow * BKK + acol] = v0;
      *(s16x8*)&sB[arow * BKK + acol + 8] = v1;
    }
    __syncthreads();
    s16x8 af[4], bfr[4];
#pragma unroll
    for (int mi = 0; mi < 4; ++mi)
      af[mi] = *(const s16x8*)&sA[(wr * 64 + mi * 16 + lr) * BKK + kg * 8];
#pragma unroll
    for (int ni = 0; ni < 4; ++ni)
      bfr[ni] = *(const s16x8*)&sB[(wc * 64 + ni * 16 + lr) * BKK + kg * 8];
#pragma unroll
    for (int mi = 0; mi < 4; ++mi)
#pragma unroll
      for (int ni = 0; ni < 4; ++ni)
        acc[mi][ni] = __builtin_amdgcn_mfma_f32_16x16x32_bf16(af[mi], bfr[ni], acc[mi][ni], 0, 0, 0);
  }
  const int r0 = bm * BM + wr * 64;
  const int c0 = bn * BN + wc * 64;
#pragma unroll
  for (int mi = 0; mi < 4; ++mi)
#pragma unroll
    for (int ni = 0; ni < 4; ++ni) {
      const int col = c0 + ni * 16 + lr;
      const float bv = bias[col];
#pragma unroll
      for (int e = 0; e < 4; ++e) {
        const int row = r0 + mi * 16 + kg * 4 + e;
        const float v = acc[mi][ni][e] + bv;
        if (C_BF16) ((unsigned short*)Cv)[(size_t)row * N + col] = f2bf(v);
        else        ((float*)Cv)[(size_t)row * N + col] = v;
      }
    }
}

// ---------------------------------------------------------------- encoder LSTM scan (pre f32 or bf16)
template<int PRE_BF16>
__global__ __launch_bounds__(512) void lstm_scan(const void* __restrict__ prev,
    const float* __restrict__ Whh, unsigned short* __restrict__ hs, int T) {
  __shared__ unsigned short hb[2][2048];
  const int tid = threadIdx.x;
  const int l = tid & 63, w = tid >> 6;
  const int wg = blockIdx.x;
  const int lr = l & 15, kg = l >> 4;
  const int col = w * 16 + lr;
  const int rbase = kg * 4;

  s16x8 wf[4][4];
#pragma unroll
  for (int gi = 0; gi < 4; ++gi)
#pragma unroll
    for (int kk = 0; kk < 4; ++kk) {
      const float* p = Whh + (size_t)(gi * 128 + col) * 128 + kk * 32 + kg * 8;
#pragma unroll
      for (int e = 0; e < 8; ++e) wf[gi][kk][e] = (short)f2bf(p[e]);
    }
  for (int i = tid; i < 4096; i += 512) ((unsigned short*)hb)[i] = 0;
  float c[4] = {0.f, 0.f, 0.f, 0.f};

  const size_t base = ((size_t)(wg * 16 + rbase)) * 512 + col;
  const float* pf32 = (const float*)prev + base;
  const unsigned short* pbf = (const unsigned short*)prev + base;
  float pf[16];
#pragma unroll
  for (int gi = 0; gi < 4; ++gi)
#pragma unroll
    for (int e = 0; e < 4; ++e)
      pf[gi * 4 + e] = PRE_BF16 ? bf2f((short)pbf[e * 512 + gi * 128]) : pf32[e * 512 + gi * 128];
  __syncthreads();

  for (int t = 0; t < T; ++t) {
    const unsigned short* hc = hb[t & 1];
    unsigned short* hn = hb[(t & 1) ^ 1];
    s16x8 a[4];
#pragma unroll
    for (int kk = 0; kk < 4; ++kk) {
      const int byt = lr * 256 + ((kk * 64 + kg * 16) ^ ((lr & 7) << 4));
      a[kk] = *(const s16x8*)((const char*)hc + byt);
    }
    f32x4 acc[4];
#pragma unroll
    for (int gi = 0; gi < 4; ++gi)
      acc[gi] = (f32x4){pf[gi * 4], pf[gi * 4 + 1], pf[gi * 4 + 2], pf[gi * 4 + 3]};
    float pfn[16];
    if (t + 1 < T) {
      const size_t ofs = (size_t)(t + 1) * 65536;
#pragma unroll
      for (int gi = 0; gi < 4; ++gi)
#pragma unroll
        for (int e = 0; e < 4; ++e)
          pfn[gi * 4 + e] = PRE_BF16 ? bf2f((short)pbf[ofs + e * 512 + gi * 128])
                                     : pf32[ofs + e * 512 + gi * 128];
    } else {
#pragma unroll
      for (int i2 = 0; i2 < 16; ++i2) pfn[i2] = 0.f;
    }
#pragma unroll
    for (int kk = 0; kk < 4; ++kk)
#pragma unroll
      for (int gi = 0; gi < 4; ++gi)
        acc[gi] = __builtin_amdgcn_mfma_f32_16x16x32_bf16(a[kk], wf[gi][kk], acc[gi], 0, 0, 0);
#pragma unroll
    for (int e = 0; e < 4; ++e) {
      float gi_ = sigf(acc[0][e]);
      float gf  = sigf(acc[1][e]);
      float gg  = tanhf_(acc[2][e]);
      float go  = sigf(acc[3][e]);
      c[e] = gf * c[e] + gi_ * gg;
      float h = go * tanhf_(c[e]);
      unsigned short hu = f2bf(h);
      int row = rbase + e;
      int byt = row * 256 + ((col * 2) ^ ((row & 7) << 4));
      *(unsigned short*)((char*)hn + byt) = hu;
      hs[((size_t)t * 128 + wg * 16 + row) * 128 + col] = hu;
    }
#pragma unroll
    for (int i2 = 0; i2 < 16; ++i2) pf[i2] = pfn[i2];
    __syncthreads();
  }
}

// ---------------------------------------------------------------- self-contained decoder v7: 6 phases
// R13 streams byte-identical (L0/L1 weights, K LDS skew-16, V scalar).
// vs R14: avp back to row-major [4][132] (pad kills the 8-way transpose conflict:
// R14's 3.8e7 SQ_LDS_BANK_CONFLICT); P7 folded into next step's P1 prologue
// (y = red-pairs + linb2, computed locally; out[s-1] written in P1; out[63] in epilogue).
// Phases: P1 L0(+y), P2 L1, P3 q, P4 scores, P5 AV, P6 Wo+lin.

#define DEC_SMEM 148768

__global__ void __launch_bounds__(512, 1) decoder_single(
    const unsigned short* __restrict__ kb, const unsigned short* __restrict__ vb,
    const unsigned* __restrict__ w0t,  const unsigned* __restrict__ wh0t,
    const unsigned* __restrict__ wi1t, const unsigned* __restrict__ wh1t,
    const unsigned* __restrict__ wqt,  const unsigned* __restrict__ wot,
    const float* __restrict__ b0, const float* __restrict__ b1,
    const float* __restrict__ bq, const float* __restrict__ bo,
    const float* __restrict__ linW, const float* __restrict__ lwcWo,
    const float* __restrict__ linb2, float* __restrict__ out)
{
  extern __shared__ char smem[];
  unsigned short* Kl = (unsigned short*)smem;      // [512 rows][16 slots x 16B] skewed
  float* xin  = (float*)(smem + 131072);           // [136]; [4..131] = ct (y not stored)
  float* h0p  = (float*)(smem + 131648);           // [2][128] ping-pong
  float* h1p  = (float*)(smem + 132672);           // [2][128] ping-pong
  float* qx   = (float*)(smem + 133696);           // [128] (pre-scaled q)
  float* sc   = (float*)(smem + 134208);           // [4][512] exp-scores
  float* avp  = (float*)(smem + 142400);           // [4][132] AV partials (padded rows)
  float* red  = (float*)(smem + 144512);           // [32]
  float* isl  = (float*)(smem + 144640);           // [4]
  float* linWhL = (float*)(smem + 144656);         // [4][128]
  float* lwcWoL = (float*)(smem + 146704);         // [4][128]
  float* linb2L = (float*)(smem + 148752);         // [4]

  const int b = blockIdx.x;
  const int tid = threadIdx.x;
  const int l = tid & 63, wv = tid >> 6;
  const int lb = l & ~3;                 // 4-lane group base
  const int gate = tid & 3, o512 = tid >> 2;
  const int oq = tid >> 2, kq = tid & 3; // quad map for q / Wo phases
  const int o128 = tid & 127, qd = tid >> 7;

  // ---- one-time K staging (R13-exact)
  {
    const unsigned* kb32 = (const unsigned*)kb;
#pragma unroll
    for (int it = 0; it < 64; ++it) {
      const int i = tid + it * 512;
      const int t = i >> 6, c32 = i & 63;
      const unsigned v = kb32[(size_t)t * 8192 + b * 64 + c32];
      const int slot = c32 >> 2, w32 = c32 & 3;
      *(unsigned*)((char*)Kl + t * 256 + (((slot + t) & 15) << 4) + w32 * 4) = v;
    }
  }
  const float b0r = b0[gate * 128 + o512];
  const float b1r = b1[gate * 128 + o512];
  const float bqv = bq[oq];
  const float bov = bo[oq];
  float cc0 = 0.f, cc1 = 0.f;

  if (tid < 136) xin[tid] = 0.f;
  if (tid < 128) { h0p[tid] = 0.f; h0p[128 + tid] = 0.f; h1p[tid] = 0.f; h1p[128 + tid] = 0.f; }
  { // stage lin weights (once)
    linWhL[tid] = linW[(size_t)qd * 256 + o128];
    lwcWoL[tid] = lwcWo[tid];
    if (tid < 4) linb2L[tid] = linb2[tid];
  }
  __syncthreads();

  const float scale = 0.1767766952966369f;  // 1/sqrt(32)

  for (int s = 0; s < 64; ++s) {
    const float* h0c = h0p + (s & 1) * 128;
    float* h0n = h0p + ((s & 1) ^ 1) * 128;
    const float* h1c = h1p + (s & 1) * 128;
    float* h1n = h1p + ((s & 1) ^ 1) * 128;

    // ======== P1: y-finalize (prev step) + layer 0
    {
      float y0, y1, y2, y3;
      if (s == 0) { y0 = y1 = y2 = y3 = 0.f; }
      else {
        y0 = red[0] + red[1] + linb2L[0];
        y1 = red[2] + red[3] + linb2L[1];
        y2 = red[4] + red[5] + linb2L[2];
        y3 = red[6] + red[7] + linb2L[3];
        if (tid < 4) {
          const float yv = red[2 * tid] + red[2 * tid + 1] + linb2L[tid];
          out[((size_t)(s - 1) * 128 + b) * 4 + tid] = yv;
        }
      }
      float a0 = b0r, a1 = 0.f;
      const unsigned* wp = w0t + tid;
      {  // kk = 0,1: xin[0..3] = y, computed locally
        const unsigned wA = wp[0];
        a0 += y0 * bflo(wA); a1 += y1 * bfhi(wA);
        const unsigned wB = wp[512];
        a0 += y2 * bflo(wB); a1 += y3 * bfhi(wB);
      }
#pragma unroll 8
      for (int kk = 2; kk < 68; ++kk) {
        const unsigned w2 = wp[kk * 512];
        const float2 x2 = *(const float2*)(xin + 2 * kk);
        a0 += x2.x * bflo(w2); a1 += x2.y * bfhi(w2);
      }
      const unsigned* hp = wh0t + tid;
#pragma unroll 8
      for (int kk = 0; kk < 64; ++kk) {
        const unsigned w2 = hp[kk * 512];
        const float2 h2 = *(const float2*)(h0c + 2 * kk);
        a0 += h2.x * bflo(w2); a1 += h2.y * bfhi(w2);
      }
      const float gval = a0 + a1;
      const float iv = __shfl(gval, lb + 0);
      const float fv = __shfl(gval, lb + 1);
      const float gv = __shfl(gval, lb + 2);
      const float ov = __shfl(gval, lb + 3);
      cc0 = sigf(fv) * cc0 + sigf(iv) * tanhf_(gv);
      const float h = sigf(ov) * tanhf_(cc0);
      if (gate == 0) h0n[o512] = h;
    }
    __syncthreads();
    // ======== P2: layer 1 (R13-exact streams)
    {
      float a0 = b1r, a1 = 0.f;
      const unsigned* ip = wi1t + tid;
      const unsigned* hp = wh1t + tid;
#pragma unroll 8
      for (int kk = 0; kk < 64; ++kk) {
        const unsigned wa = ip[kk * 512];
        const unsigned wb = hp[kk * 512];
        const float2 a2 = *(const float2*)(h0n + 2 * kk);
        const float2 b2 = *(const float2*)(h1c + 2 * kk);
        a0 += a2.x * bflo(wa) + b2.x * bflo(wb);
        a1 += a2.y * bfhi(wa) + b2.y * bfhi(wb);
      }
      const float gval = a0 + a1;
      const float iv = __shfl(gval, lb + 0);
      const float fv = __shfl(gval, lb + 1);
      const float gv = __shfl(gval, lb + 2);
      const float ov = __shfl(gval, lb + 3);
      cc1 = sigf(fv) * cc1 + sigf(iv) * tanhf_(gv);
      const float h = sigf(ov) * tanhf_(cc1);
      if (gate == 0) h1n[o512] = h;
    }
    __syncthreads();
    // ======== P3: q = Wq.h1 (quad-lane K-split, shfl reduce)
    {
      float a0 = 0.f, a1 = 0.f;
      const unsigned* wp = wqt + (size_t)(kq * 16) * 128 + oq;
#pragma unroll
      for (int m = 0; m < 16; ++m) {
        const unsigned w2 = wp[(size_t)m * 128];
        const float2 h2 = *(const float2*)(h1n + kq * 32 + 2 * m);
        a0 += h2.x * bflo(w2);
        a1 += h2.y * bfhi(w2);
      }
      float p = a0 + a1;
      p += __shfl_xor(p, 1);
      p += __shfl_xor(p, 2);
      if (kq == 0) qx[oq] = (bqv + p) * scale;
    }
    __syncthreads();
    // ======== P4: scores (exp, no max-sub) + wave sums (R13-exact)
    {
      const int t = tid;
      float s0 = 0.f, s1 = 0.f, s2 = 0.f, s3 = 0.f;
      const char* krow = (const char*)Kl + t * 256;
#pragma unroll
      for (int c = 0; c < 16; ++c) {
        const s16x8 kv = *(const s16x8*)(krow + (((c + t) & 15) << 4));
        const f32x4 qA = *(const f32x4*)(qx + c * 8);
        const f32x4 qB = *(const f32x4*)(qx + c * 8 + 4);
        float d = qA[0] * bf2f(kv[0]) + qA[1] * bf2f(kv[1]) + qA[2] * bf2f(kv[2]) + qA[3] * bf2f(kv[3])
                + qB[0] * bf2f(kv[4]) + qB[1] * bf2f(kv[5]) + qB[2] * bf2f(kv[6]) + qB[3] * bf2f(kv[7]);
        if ((c >> 2) == 0) s0 += d; else if ((c >> 2) == 1) s1 += d; else if ((c >> 2) == 2) s2 += d; else s3 += d;
      }
      float p0 = __expf(s0), p1 = __expf(s1), p2 = __expf(s2), p3 = __expf(s3);
      sc[0 * 512 + t] = p0; sc[1 * 512 + t] = p1; sc[2 * 512 + t] = p2; sc[3 * 512 + t] = p3;
#pragma unroll
      for (int off = 32; off > 0; off >>= 1) {
        p0 += __shfl_xor(p0, off); p1 += __shfl_xor(p1, off);
        p2 += __shfl_xor(p2, off); p3 += __shfl_xor(p3, off);
      }
      if (l == 0) { red[0 + wv] = p0; red[8 + wv] = p1; red[16 + wv] = p2; red[24 + wv] = p3; }
    }
    __syncthreads();
    // ======== P5: AV partials (R13-exact V stream) -> avp[tc][d] (rows padded to 132)
    if (tid < 4) {
      float sm = red[tid * 8];
#pragma unroll
      for (int w2 = 1; w2 < 8; ++w2) sm += red[tid * 8 + w2];
      isl[tid] = 1.f / sm;
    }
    {
      const int d = tid & 127, tc = tid >> 7, h = d >> 5;
      const unsigned short* vp = vb + (size_t)(tc * 128) * 16384 + (size_t)b * 128 + d;
      const float* scp = sc + h * 512 + tc * 128;
      float acc = 0.f;
#pragma unroll 8
      for (int tt = 0; tt < 128; ++tt)
        acc += scp[tt] * bf2f((short)vp[(size_t)tt * 16384]);
      avp[tc * 132 + d] = acc;
    }
    __syncthreads();
    // ======== P6: Wo (quad-lane, ctv on the fly) -> xin[4..];  lin partials -> red
    {
      const float iq = isl[kq];
      float a0 = 0.f, a1 = 0.f;
      const unsigned* wp = wot + (size_t)(kq * 16) * 128 + oq;
#pragma unroll
      for (int m = 0; m < 16; ++m) {
        const unsigned w2 = wp[(size_t)m * 128];
        const int k2 = kq * 32 + 2 * m;
        float c0v = 0.f, c1v = 0.f;
#pragma unroll
        for (int t4 = 0; t4 < 4; ++t4) {
          const float2 v2 = *(const float2*)(avp + t4 * 132 + k2);
          c0v += v2.x; c1v += v2.y;
        }
        a0 += c0v * iq * bflo(w2);
        a1 += c1v * iq * bfhi(w2);
      }
      float p = a0 + a1;
      p += __shfl_xor(p, 1);
      p += __shfl_xor(p, 2);
      if (kq == 0) xin[4 + oq] = bov + p;
    }
    {
      // lin: thread (qd, j); y = linWh.h1 + lwcWo.ctv + linb2 (finalized next P1)
      const int j = o128;
      const float ctvj = (avp[j] + avp[132 + j] + avp[264 + j] + avp[396 + j]) * isl[j >> 5];
      float p = h1n[j] * linWhL[qd * 128 + j] + ctvj * lwcWoL[qd * 128 + j];
#pragma unroll
      for (int off = 32; off > 0; off >>= 1) p += __shfl_xor(p, off);
      if (l == 0) red[wv] = p;
    }
    __syncthreads();
  }
  // epilogue: final y (step 63)
  if (tid < 4) {
    const float yv = red[2 * tid] + red[2 * tid + 1] + linb2L[tid];
    out[((size_t)63 * 128 + b) * 4 + tid] = yv;
  }
}

// ---------------------------------------------------------------- launch
extern "C" void kernel_launch(void* const* d_in, const int* in_sizes, int n_in,
                              void* d_out, int out_size, void* d_ws, size_t ws_size,
                              hipStream_t stream) {
  (void)in_sizes; (void)n_in; (void)out_size;
  const float* x     = (const float*)d_in[0];
  const float* eWih0 = (const float*)d_in[1];
  const float* eWhh0 = (const float*)d_in[2];
  const float* eb0   = (const float*)d_in[3];
  const float* eWih1 = (const float*)d_in[4];
  const float* eWhh1 = (const float*)d_in[5];
  const float* eb1   = (const float*)d_in[6];
  const float* dWih0 = (const float*)d_in[7];
  const float* dWhh0 = (const float*)d_in[8];
  const float* db0   = (const float*)d_in[9];
  const float* dWih1 = (const float*)d_in[10];
  const float* dWhh1 = (const float*)d_in[11];
  const float* db1   = (const float*)d_in[12];
  const float* Wq    = (const float*)d_in[13];
  const float* bq    = (const float*)d_in[14];
  const float* Wk    = (const float*)d_in[15];
  const float* bk    = (const float*)d_in[16];
  const float* Wv    = (const float*)d_in[17];
  const float* bv    = (const float*)d_in[18];
  const float* Wo    = (const float*)d_in[19];
  const float* bo    = (const float*)d_in[20];
  const float* linW  = (const float*)d_in[21];
  const float* linb  = (const float*)d_in[22];

  char* w = (char*)d_ws;
  float* pre  = (float*)(w + 524288);                    // 128 MB (pre0 f32; pre1 bf16 reuses it)
  size_t off = 524288 + (size_t)65536 * 512 * 4;
  unsigned short* hs0  = (unsigned short*)(w + off); off += (size_t)65536 * 128 * 2;
  unsigned short* enc  = (unsigned short*)(w + off); off += (size_t)65536 * 128 * 2;
  unsigned short* kbuf = (unsigned short*)(w + off); off += (size_t)65536 * 128 * 2;
  unsigned short* vbuf = (unsigned short*)(w + off); off += (size_t)65536 * 128 * 2;
  unsigned* w0t  = (unsigned*)(w + off); off += (size_t)68 * 512 * 4;
  unsigned* wh0t = (unsigned*)(w + off); off += (size_t)64 * 512 * 4;
  unsigned* wi1t = (unsigned*)(w + off); off += (size_t)64 * 512 * 4;
  unsigned* wh1t = (unsigned*)(w + off); off += (size_t)64 * 512 * 4;
  unsigned* wqt  = (unsigned*)(w + off); off += (size_t)64 * 128 * 4;
  unsigned* wot  = (unsigned*)(w + off); off += (size_t)64 * 128 * 4;
  float* lwcWo   = (float*)(w + off);    off += 4 * 128 * 4;
  float* linb2   = (float*)(w + off);    off += 64;
  unsigned short* xbf = (unsigned short*)(w + off);
  const size_t need_big = off + (size_t)65536 * 1024 * 2;
  const bool big = ws_size >= need_big;

  // decoder weight packing (R13-identical)
  packTg<<<(68 * 512 + 255) / 256, 256, 0, stream>>>(dWih0, w0t, 132, 68);
  packTg<<<(64 * 512 + 255) / 256, 256, 0, stream>>>(dWhh0, wh0t, 128, 64);
  packTg<<<(64 * 512 + 255) / 256, 256, 0, stream>>>(dWih1, wi1t, 128, 64);
  packTg<<<(64 * 512 + 255) / 256, 256, 0, stream>>>(dWhh1, wh1t, 128, 64);
  packT<<<(64 * 128 + 255) / 256, 256, 0, stream>>>(Wq, wqt, 128, 128, 64);
  packT<<<(64 * 128 + 255) / 256, 256, 0, stream>>>(Wo, wot, 128, 128, 64);
  foldWo<<<1, 512, 0, stream>>>(linW, Wo, bo, linb, lwcWo, linb2);

  // encoder
  if (big) {
    f2bf_vec<<<65536, 256, 0, stream>>>(x, xbf);
    gemm_bt<1, 0><<<dim3(4, 512), 256, 0, stream>>>((const void*)xbf, eWih0, eb0, (void*)pre, 65536, 512, 1024);
  } else {
    gemm_bt<0, 0><<<dim3(4, 512), 256, 0, stream>>>((const void*)x, eWih0, eb0, (void*)pre, 65536, 512, 1024);
  }
  lstm_scan<0><<<8, 512, 0, stream>>>((const void*)pre, eWhh0, hs0, 512);
  // layer-1 pre in bf16 (halves gemm2 write + scan1 read traffic)
  gemm_bt<1, 1><<<dim3(4, 512), 256, 0, stream>>>((const void*)hs0, eWih1, eb1, (void*)pre, 65536, 512, 128);
  lstm_scan<1><<<8, 512, 0, stream>>>((const void*)pre, eWhh1, enc, 512);
  // K/V projections
  gemm_bt<1, 1><<<dim3(1, 512), 256, 0, stream>>>((const void*)enc, Wk, bk, (void*)kbuf, 65536, 128, 128);
  gemm_bt<1, 1><<<dim3(1, 512), 256, 0, stream>>>((const void*)enc, Wv, bv, (void*)vbuf, 65536, 128, 128);

  // self-contained decoder: 128 WGs, one per batch, 6 phases/step
  hipFuncSetAttribute((const void*)decoder_single,
                      hipFuncAttributeMaxDynamicSharedMemorySize, DEC_SMEM);
  decoder_single<<<128, 512, DEC_SMEM, stream>>>(kbuf, vbuf, w0t, wh0t, wi1t, wh1t, wqt, wot,
      db0, db1, bq, bo, linW, lwcWo, linb2, (float*)d_out);
}

// Round 16
// 3709.686 us; speedup vs baseline: 1.0594x; 1.0594x over previous
//
#include <hip/hip_runtime.h>
#include <hip/hip_bf16.h>

typedef __attribute__((ext_vector_type(8))) short s16x8;
typedef __attribute__((ext_vector_type(4))) float f32x4;

__device__ inline unsigned short f2bf(float f) {
  unsigned u = __builtin_bit_cast(unsigned, f);
  unsigned r = (u + 0x7FFFu + ((u >> 16) & 1u)) >> 16;  // RTNE
  return (unsigned short)r;
}
__device__ inline float bf2f(short v) {
  return __builtin_bit_cast(float, ((unsigned)(unsigned short)v) << 16);
}
__device__ inline float bflo(unsigned w) { return __builtin_bit_cast(float, w << 16); }
__device__ inline float bfhi(unsigned w) { return __builtin_bit_cast(float, w & 0xFFFF0000u); }
__device__ inline float sigf(float x) { return 1.f / (1.f + __expf(-x)); }
__device__ inline float tanhf_(float x) { float e = __expf(2.f * x); return 1.f - 2.f / (e + 1.f); }

// ---------------------------------------------------------------- packers (R13-identical streams)
__global__ void packT(const float* __restrict__ src, unsigned* __restrict__ dst,
                      int rows, int scols, int kkPairs) {
  int i = blockIdx.x * 256 + threadIdx.x;
  if (i >= kkPairs * rows) return;
  int kk = i / rows, o = i % rows;
  int k0 = 2 * kk, k1 = 2 * kk + 1;
  float lo = (k0 < scols) ? src[(size_t)o * scols + k0] : 0.f;
  float hi = (k1 < scols) ? src[(size_t)o * scols + k1] : 0.f;
  dst[i] = (unsigned)f2bf(lo) | ((unsigned)f2bf(hi) << 16);
}
__global__ void packTg(const float* __restrict__ src, unsigned* __restrict__ dst,
                       int scols, int kkPairs) {
  int i = blockIdx.x * 256 + threadIdx.x;
  if (i >= kkPairs * 512) return;
  int kk = i / 512, j = i % 512;
  int row = (j & 3) * 128 + (j >> 2);
  int k0 = 2 * kk, k1 = 2 * kk + 1;
  float lo = (k0 < scols) ? src[(size_t)row * scols + k0] : 0.f;
  float hi = (k1 < scols) ? src[(size_t)row * scols + k1] : 0.f;
  dst[i] = (unsigned)f2bf(lo) | ((unsigned)f2bf(hi) << 16);
}
__global__ void f2bf_vec(const float* __restrict__ src, unsigned short* __restrict__ dst) {
  size_t i = ((size_t)blockIdx.x * 256 + threadIdx.x) * 4;
  float4 v = *(const float4*)(src + i);
  ushort4 o;
  o.x = f2bf(v.x); o.y = f2bf(v.y); o.z = f2bf(v.z); o.w = f2bf(v.w);
  *(ushort4*)(dst + i) = o;
}
// fold lin_c into Wo:  lwcWo[o4][k] = sum_j linW[o4][128+j]*Wo[j][k];  linb2 = linb + linW_c . bo
__global__ void foldWo(const float* __restrict__ linW, const float* __restrict__ Wo,
                       const float* __restrict__ bo, const float* __restrict__ linb,
                       float* __restrict__ lwcWo, float* __restrict__ linb2) {
  const int tid = threadIdx.x;              // 512
  const int o4 = tid >> 7, k = tid & 127;
  float acc = 0.f;
  for (int j = 0; j < 128; ++j) acc += linW[o4 * 256 + 128 + j] * Wo[(size_t)j * 128 + k];
  lwcWo[o4 * 128 + k] = acc;
  if (k == 0) {
    float a2 = linb[o4];
    for (int j = 0; j < 128; ++j) a2 += linW[o4 * 256 + 128 + j] * bo[j];
    linb2[o4] = a2;
  }
}

// ---------------------------------------------------------------- GEMM C = A @ B^T + bias
#define BM 128
#define BN 128
#define BKK 32

template<int A_BF16, int C_BF16>
__global__ __launch_bounds__(256) void gemm_bt(const void* __restrict__ Av,
    const float* __restrict__ B, const float* __restrict__ bias,
    void* __restrict__ Cv, int M, int N, int K) {
  __shared__ short sA[BM * BKK];
  __shared__ short sB[BN * BKK];
  const int tid = threadIdx.x;
  const int l = tid & 63;
  const int wid = tid >> 6;
  const int wr = wid >> 1, wc = wid & 1;
  const int lr = l & 15, kg = l >> 4;
  const int bn = blockIdx.x, bm = blockIdx.y;
  const int arow = tid >> 1;
  const int acol = (tid & 1) * 16;

  f32x4 acc[4][4];
#pragma unroll
  for (int i = 0; i < 4; ++i)
#pragma unroll
    for (int j = 0; j < 4; ++j) acc[i][j] = (f32x4){0.f, 0.f, 0.f, 0.f};

  for (int kt = 0; kt < K; kt += BKK) {
    __syncthreads();
    if (A_BF16) {
      const unsigned short* src = (const unsigned short*)Av + (size_t)(bm * BM + arow) * K + kt + acol;
      *(s16x8*)&sA[arow * BKK + acol] = *(const s16x8*)src;
      *(s16x8*)&sA[arow * BKK + acol + 8] = *(const s16x8*)(src + 8);
    } else {
      const float* src = (const float*)Av + (size_t)(bm * BM + arow) * K + kt + acol;
      s16x8 v0, v1;
#pragma unroll
      for (int e = 0; e < 8; ++e) { v0[e] = (short)f2bf(src[e]); v1[e] = (short)f2bf(src[8 + e]); }
      *(s16x8*)&sA[arow * BKK + acol] = v0;
      *(s16x8*)&sA[arow * BKK + acol + 8] = v1;
    }
    {
      const float* src = B + (size_t)(bn * BN + arow) * K + kt + acol;
      s16x8 v0, v1;
#pragma unroll
      for (int e = 0; e < 8; ++e) { v0[e] = (short)f2bf(src[e]); v1[e] = (short)f2bf(src[8 + e]); }
      *(s16x8*)&sB[arow * BKK + acol] = v0;
      *(s16x8*)&sB[arow * BKK + acol + 8] = v1;
    }
    __syncthreads();
    s16x8 af[4], bfr[4];
#pragma unroll
    for (int mi = 0; mi < 4; ++mi)
      af[mi] = *(const s16x8*)&sA[(wr * 64 + mi * 16 + lr) * BKK + kg * 8];
#pragma unroll
    for (int ni = 0; ni < 4; ++ni)
      bfr[ni] = *(const s16x8*)&sB[(wc * 64 + ni * 16 + lr) * BKK + kg * 8];
#pragma unroll
    for (int mi = 0; mi < 4; ++mi)
#pragma unroll
      for (int ni = 0; ni < 4; ++ni)
        acc[mi][ni] = __builtin_amdgcn_mfma_f32_16x16x32_bf16(af[mi], bfr[ni], acc[mi][ni], 0, 0, 0);
  }
  const int r0 = bm * BM + wr * 64;
  const int c0 = bn * BN + wc * 64;
#pragma unroll
  for (int mi = 0; mi < 4; ++mi)
#pragma unroll
    for (int ni = 0; ni < 4; ++ni) {
      const int col = c0 + ni * 16 + lr;
      const float bv = bias[col];
#pragma unroll
      for (int e = 0; e < 4; ++e) {
        const int row = r0 + mi * 16 + kg * 4 + e;
        const float v = acc[mi][ni][e] + bv;
        if (C_BF16) ((unsigned short*)Cv)[(size_t)row * N + col] = f2bf(v);
        else        ((float*)Cv)[(size_t)row * N + col] = v;
      }
    }
}

// ---------------------------------------------------------------- encoder LSTM scan (pre f32 or bf16)
template<int PRE_BF16>
__global__ __launch_bounds__(512) void lstm_scan(const void* __restrict__ prev,
    const float* __restrict__ Whh, unsigned short* __restrict__ hs, int T) {
  __shared__ unsigned short hb[2][2048];
  const int tid = threadIdx.x;
  const int l = tid & 63, w = tid >> 6;
  const int wg = blockIdx.x;
  const int lr = l & 15, kg = l >> 4;
  const int col = w * 16 + lr;
  const int rbase = kg * 4;

  s16x8 wf[4][4];
#pragma unroll
  for (int gi = 0; gi < 4; ++gi)
#pragma unroll
    for (int kk = 0; kk < 4; ++kk) {
      const float* p = Whh + (size_t)(gi * 128 + col) * 128 + kk * 32 + kg * 8;
#pragma unroll
      for (int e = 0; e < 8; ++e) wf[gi][kk][e] = (short)f2bf(p[e]);
    }
  for (int i = tid; i < 4096; i += 512) ((unsigned short*)hb)[i] = 0;
  float c[4] = {0.f, 0.f, 0.f, 0.f};

  const size_t base = ((size_t)(wg * 16 + rbase)) * 512 + col;
  const float* pf32 = (const float*)prev + base;
  const unsigned short* pbf = (const unsigned short*)prev + base;
  float pf[16];
#pragma unroll
  for (int gi = 0; gi < 4; ++gi)
#pragma unroll
    for (int e = 0; e < 4; ++e)
      pf[gi * 4 + e] = PRE_BF16 ? bf2f((short)pbf[e * 512 + gi * 128]) : pf32[e * 512 + gi * 128];
  __syncthreads();

  for (int t = 0; t < T; ++t) {
    const unsigned short* hc = hb[t & 1];
    unsigned short* hn = hb[(t & 1) ^ 1];
    s16x8 a[4];
#pragma unroll
    for (int kk = 0; kk < 4; ++kk) {
      const int byt = lr * 256 + ((kk * 64 + kg * 16) ^ ((lr & 7) << 4));
      a[kk] = *(const s16x8*)((const char*)hc + byt);
    }
    f32x4 acc[4];
#pragma unroll
    for (int gi = 0; gi < 4; ++gi)
      acc[gi] = (f32x4){pf[gi * 4], pf[gi * 4 + 1], pf[gi * 4 + 2], pf[gi * 4 + 3]};
    float pfn[16];
    if (t + 1 < T) {
      const size_t ofs = (size_t)(t + 1) * 65536;
#pragma unroll
      for (int gi = 0; gi < 4; ++gi)
#pragma unroll
        for (int e = 0; e < 4; ++e)
          pfn[gi * 4 + e] = PRE_BF16 ? bf2f((short)pbf[ofs + e * 512 + gi * 128])
                                     : pf32[ofs + e * 512 + gi * 128];
    } else {
#pragma unroll
      for (int i2 = 0; i2 < 16; ++i2) pfn[i2] = 0.f;
    }
#pragma unroll
    for (int kk = 0; kk < 4; ++kk)
#pragma unroll
      for (int gi = 0; gi < 4; ++gi)
        acc[gi] = __builtin_amdgcn_mfma_f32_16x16x32_bf16(a[kk], wf[gi][kk], acc[gi], 0, 0, 0);
#pragma unroll
    for (int e = 0; e < 4; ++e) {
      float gi_ = sigf(acc[0][e]);
      float gf  = sigf(acc[1][e]);
      float gg  = tanhf_(acc[2][e]);
      float go  = sigf(acc[3][e]);
      c[e] = gf * c[e] + gi_ * gg;
      float h = go * tanhf_(c[e]);
      unsigned short hu = f2bf(h);
      int row = rbase + e;
      int byt = row * 256 + ((col * 2) ^ ((row & 7) << 4));
      *(unsigned short*)((char*)hn + byt) = hu;
      hs[((size_t)t * 128 + wg * 16 + row) * 128 + col] = hu;
    }
#pragma unroll
    for (int i2 = 0; i2 < 16; ++i2) pf[i2] = pfn[i2];
    __syncthreads();
  }
}

// ---------------------------------------------------------------- self-contained decoder v8: 6 phases, conflict-free
// vs R15: P3/P6 quad-lane K-split FINE-INTERLEAVED (k2 = 8m + 2*kq, kk = 4m + kq).
// R15's k2 = kq*32+2m put all 4 kq-lane-groups in the SAME bank (128B stride) ->
// 4-way conflict per read (6.3e7 conflict cycles). With 2kq in the low bank bits,
// the 4 groups land in banks 0/2/4/6 -> conflict-free. Same wqt/wot buffers,
// different traversal. All other streams R13-byte-identical.

#define DEC_SMEM 148768

__global__ void __launch_bounds__(512, 1) decoder_single(
    const unsigned short* __restrict__ kb, const unsigned short* __restrict__ vb,
    const unsigned* __restrict__ w0t,  const unsigned* __restrict__ wh0t,
    const unsigned* __restrict__ wi1t, const unsigned* __restrict__ wh1t,
    const unsigned* __restrict__ wqt,  const unsigned* __restrict__ wot,
    const float* __restrict__ b0, const float* __restrict__ b1,
    const float* __restrict__ bq, const float* __restrict__ bo,
    const float* __restrict__ linW, const float* __restrict__ lwcWo,
    const float* __restrict__ linb2, float* __restrict__ out)
{
  extern __shared__ char smem[];
  unsigned short* Kl = (unsigned short*)smem;      // [512 rows][16 slots x 16B] skewed
  float* xin  = (float*)(smem + 131072);           // [136]; [4..131] = ct (y not stored)
  float* h0p  = (float*)(smem + 131648);           // [2][128] ping-pong
  float* h1p  = (float*)(smem + 132672);           // [2][128] ping-pong
  float* qx   = (float*)(smem + 133696);           // [128] (pre-scaled q)
  float* sc   = (float*)(smem + 134208);           // [4][512] exp-scores
  float* avp  = (float*)(smem + 142400);           // [4][132] AV partials (padded rows)
  float* red  = (float*)(smem + 144512);           // [32]
  float* isl  = (float*)(smem + 144640);           // [4]
  float* linWhL = (float*)(smem + 144656);         // [4][128]
  float* lwcWoL = (float*)(smem + 146704);         // [4][128]
  float* linb2L = (float*)(smem + 148752);         // [4]

  const int b = blockIdx.x;
  const int tid = threadIdx.x;
  const int l = tid & 63, wv = tid >> 6;
  const int lb = l & ~3;                 // 4-lane group base
  const int gate = tid & 3, o512 = tid >> 2;
  const int oq = tid >> 2, kq = tid & 3; // quad map for q / Wo phases
  const int o128 = tid & 127, qd = tid >> 7;

  // ---- one-time K staging (R13-exact)
  {
    const unsigned* kb32 = (const unsigned*)kb;
#pragma unroll
    for (int it = 0; it < 64; ++it) {
      const int i = tid + it * 512;
      const int t = i >> 6, c32 = i & 63;
      const unsigned v = kb32[(size_t)t * 8192 + b * 64 + c32];
      const int slot = c32 >> 2, w32 = c32 & 3;
      *(unsigned*)((char*)Kl + t * 256 + (((slot + t) & 15) << 4) + w32 * 4) = v;
    }
  }
  const float b0r = b0[gate * 128 + o512];
  const float b1r = b1[gate * 128 + o512];
  const float bqv = bq[oq];
  const float bov = bo[oq];
  float cc0 = 0.f, cc1 = 0.f;

  if (tid < 136) xin[tid] = 0.f;
  if (tid < 128) { h0p[tid] = 0.f; h0p[128 + tid] = 0.f; h1p[tid] = 0.f; h1p[128 + tid] = 0.f; }
  { // stage lin weights (once)
    linWhL[tid] = linW[(size_t)qd * 256 + o128];
    lwcWoL[tid] = lwcWo[tid];
    if (tid < 4) linb2L[tid] = linb2[tid];
  }
  __syncthreads();

  const float scale = 0.1767766952966369f;  // 1/sqrt(32)

  for (int s = 0; s < 64; ++s) {
    const float* h0c = h0p + (s & 1) * 128;
    float* h0n = h0p + ((s & 1) ^ 1) * 128;
    const float* h1c = h1p + (s & 1) * 128;
    float* h1n = h1p + ((s & 1) ^ 1) * 128;

    // ======== P1: y-finalize (prev step) + layer 0
    {
      float y0, y1, y2, y3;
      if (s == 0) { y0 = y1 = y2 = y3 = 0.f; }
      else {
        y0 = red[0] + red[1] + linb2L[0];
        y1 = red[2] + red[3] + linb2L[1];
        y2 = red[4] + red[5] + linb2L[2];
        y3 = red[6] + red[7] + linb2L[3];
        if (tid < 4) {
          const float yv = red[2 * tid] + red[2 * tid + 1] + linb2L[tid];
          out[((size_t)(s - 1) * 128 + b) * 4 + tid] = yv;
        }
      }
      float a0 = b0r, a1 = 0.f;
      const unsigned* wp = w0t + tid;
      {  // kk = 0,1: xin[0..3] = y, computed locally
        const unsigned wA = wp[0];
        a0 += y0 * bflo(wA); a1 += y1 * bfhi(wA);
        const unsigned wB = wp[512];
        a0 += y2 * bflo(wB); a1 += y3 * bfhi(wB);
      }
#pragma unroll 8
      for (int kk = 2; kk < 68; ++kk) {
        const unsigned w2 = wp[kk * 512];
        const float2 x2 = *(const float2*)(xin + 2 * kk);
        a0 += x2.x * bflo(w2); a1 += x2.y * bfhi(w2);
      }
      const unsigned* hp = wh0t + tid;
#pragma unroll 8
      for (int kk = 0; kk < 64; ++kk) {
        const unsigned w2 = hp[kk * 512];
        const float2 h2 = *(const float2*)(h0c + 2 * kk);
        a0 += h2.x * bflo(w2); a1 += h2.y * bfhi(w2);
      }
      const float gval = a0 + a1;
      const float iv = __shfl(gval, lb + 0);
      const float fv = __shfl(gval, lb + 1);
      const float gv = __shfl(gval, lb + 2);
      const float ov = __shfl(gval, lb + 3);
      cc0 = sigf(fv) * cc0 + sigf(iv) * tanhf_(gv);
      const float h = sigf(ov) * tanhf_(cc0);
      if (gate == 0) h0n[o512] = h;
    }
    __syncthreads();
    // ======== P2: layer 1 (R13-exact streams)
    {
      float a0 = b1r, a1 = 0.f;
      const unsigned* ip = wi1t + tid;
      const unsigned* hp = wh1t + tid;
#pragma unroll 8
      for (int kk = 0; kk < 64; ++kk) {
        const unsigned wa = ip[kk * 512];
        const unsigned wb = hp[kk * 512];
        const float2 a2 = *(const float2*)(h0n + 2 * kk);
        const float2 b2 = *(const float2*)(h1c + 2 * kk);
        a0 += a2.x * bflo(wa) + b2.x * bflo(wb);
        a1 += a2.y * bfhi(wa) + b2.y * bfhi(wb);
      }
      const float gval = a0 + a1;
      const float iv = __shfl(gval, lb + 0);
      const float fv = __shfl(gval, lb + 1);
      const float gv = __shfl(gval, lb + 2);
      const float ov = __shfl(gval, lb + 3);
      cc1 = sigf(fv) * cc1 + sigf(iv) * tanhf_(gv);
      const float h = sigf(ov) * tanhf_(cc1);
      if (gate == 0) h1n[o512] = h;
    }
    __syncthreads();
    // ======== P3: q = Wq.h1 (quad-lane K-split, FINE-interleaved: kk = 4m+kq)
    {
      float a0 = 0.f, a1 = 0.f;
      const unsigned* wp = wqt + (size_t)kq * 128 + oq;
#pragma unroll
      for (int m = 0; m < 16; ++m) {
        const unsigned w2 = wp[(size_t)m * 512];
        const float2 h2 = *(const float2*)(h1n + 8 * m + 2 * kq);  // banks 2kq..2kq+1: conflict-free
        a0 += h2.x * bflo(w2);
        a1 += h2.y * bfhi(w2);
      }
      float p = a0 + a1;
      p += __shfl_xor(p, 1);
      p += __shfl_xor(p, 2);
      if (kq == 0) qx[oq] = (bqv + p) * scale;
    }
    __syncthreads();
    // ======== P4: scores (exp, no max-sub) + wave sums (R13-exact)
    {
      const int t = tid;
      float s0 = 0.f, s1 = 0.f, s2 = 0.f, s3 = 0.f;
      const char* krow = (const char*)Kl + t * 256;
#pragma unroll
      for (int c = 0; c < 16; ++c) {
        const s16x8 kv = *(const s16x8*)(krow + (((c + t) & 15) << 4));
        const f32x4 qA = *(const f32x4*)(qx + c * 8);
        const f32x4 qB = *(const f32x4*)(qx + c * 8 + 4);
        float d = qA[0] * bf2f(kv[0]) + qA[1] * bf2f(kv[1]) + qA[2] * bf2f(kv[2]) + qA[3] * bf2f(kv[3])
                + qB[0] * bf2f(kv[4]) + qB[1] * bf2f(kv[5]) + qB[2] * bf2f(kv[6]) + qB[3] * bf2f(kv[7]);
        if ((c >> 2) == 0) s0 += d; else if ((c >> 2) == 1) s1 += d; else if ((c >> 2) == 2) s2 += d; else s3 += d;
      }
      float p0 = __expf(s0), p1 = __expf(s1), p2 = __expf(s2), p3 = __expf(s3);
      sc[0 * 512 + t] = p0; sc[1 * 512 + t] = p1; sc[2 * 512 + t] = p2; sc[3 * 512 + t] = p3;
#pragma unroll
      for (int off = 32; off > 0; off >>= 1) {
        p0 += __shfl_xor(p0, off); p1 += __shfl_xor(p1, off);
        p2 += __shfl_xor(p2, off); p3 += __shfl_xor(p3, off);
      }
      if (l == 0) { red[0 + wv] = p0; red[8 + wv] = p1; red[16 + wv] = p2; red[24 + wv] = p3; }
    }
    __syncthreads();
    // ======== P5: AV partials (R13-exact V stream) -> avp[tc][d] (rows padded to 132)
    if (tid < 4) {
      float sm = red[tid * 8];
#pragma unroll
      for (int w2 = 1; w2 < 8; ++w2) sm += red[tid * 8 + w2];
      isl[tid] = 1.f / sm;
    }
    {
      const int d = tid & 127, tc = tid >> 7, h = d >> 5;
      const unsigned short* vp = vb + (size_t)(tc * 128) * 16384 + (size_t)b * 128 + d;
      const float* scp = sc + h * 512 + tc * 128;
      float acc = 0.f;
#pragma unroll 8
      for (int tt = 0; tt < 128; ++tt)
        acc += scp[tt] * bf2f((short)vp[(size_t)tt * 16384]);
      avp[tc * 132 + d] = acc;
    }
    __syncthreads();
    // ======== P6: Wo (quad-lane, fine-interleaved) -> xin[4..];  lin partials -> red
    {
      const float iq = isl[(8 * 0 + 2 * kq) >> 5];  // placeholder (head derived per k below)
      float a0 = 0.f, a1 = 0.f;
      const unsigned* wp = wot + (size_t)kq * 128 + oq;
#pragma unroll
      for (int m = 0; m < 16; ++m) {
        const unsigned w2 = wp[(size_t)m * 512];
        const int k2 = 8 * m + 2 * kq;               // banks 2kq..: conflict-free
        const float ih = isl[k2 >> 5];
        float c0v = 0.f, c1v = 0.f;
#pragma unroll
        for (int t4 = 0; t4 < 4; ++t4) {
          const float2 v2 = *(const float2*)(avp + t4 * 132 + k2);
          c0v += v2.x; c1v += v2.y;
        }
        a0 += c0v * ih * bflo(w2);
        a1 += c1v * ih * bfhi(w2);
      }
      (void)iq;
      float p = a0 + a1;
      p += __shfl_xor(p, 1);
      p += __shfl_xor(p, 2);
      if (kq == 0) xin[4 + oq] = bov + p;
    }
    {
      // lin: thread (qd, j); y = linWh.h1 + lwcWo.ctv + linb2 (finalized next P1)
      const int j = o128;
      const float ctvj = (avp[j] + avp[132 + j] + avp[264 + j] + avp[396 + j]) * isl[j >> 5];
      float p = h1n[j] * linWhL[qd * 128 + j] + ctvj * lwcWoL[qd * 128 + j];
#pragma unroll
      for (int off = 32; off > 0; off >>= 1) p += __shfl_xor(p, off);
      if (l == 0) red[wv] = p;
    }
    __syncthreads();
  }
  // epilogue: final y (step 63)
  if (tid < 4) {
    const float yv = red[2 * tid] + red[2 * tid + 1] + linb2L[tid];
    out[((size_t)63 * 128 + b) * 4 + tid] = yv;
  }
}

// ---------------------------------------------------------------- launch
extern "C" void kernel_launch(void* const* d_in, const int* in_sizes, int n_in,
                              void* d_out, int out_size, void* d_ws, size_t ws_size,
                              hipStream_t stream) {
  (void)in_sizes; (void)n_in; (void)out_size;
  const float* x     = (const float*)d_in[0];
  const float* eWih0 = (const float*)d_in[1];
  const float* eWhh0 = (const float*)d_in[2];
  const float* eb0   = (const float*)d_in[3];
  const float* eWih1 = (const float*)d_in[4];
  const float* eWhh1 = (const float*)d_in[5];
  const float* eb1   = (const float*)d_in[6];
  const float* dWih0 = (const float*)d_in[7];
  const float* dWhh0 = (const float*)d_in[8];
  const float* db0   = (const float*)d_in[9];
  const float* dWih1 = (const float*)d_in[10];
  const float* dWhh1 = (const float*)d_in[11];
  const float* db1   = (const float*)d_in[12];
  const float* Wq    = (const float*)d_in[13];
  const float* bq    = (const float*)d_in[14];
  const float* Wk    = (const float*)d_in[15];
  const float* bk    = (const float*)d_in[16];
  const float* Wv    = (const float*)d_in[17];
  const float* bv    = (const float*)d_in[18];
  const float* Wo    = (const float*)d_in[19];
  const float* bo    = (const float*)d_in[20];
  const float* linW  = (const float*)d_in[21];
  const float* linb  = (const float*)d_in[22];

  char* w = (char*)d_ws;
  float* pre  = (float*)(w + 524288);                    // 128 MB (pre0 f32; pre1 bf16 reuses it)
  size_t off = 524288 + (size_t)65536 * 512 * 4;
  unsigned short* hs0  = (unsigned short*)(w + off); off += (size_t)65536 * 128 * 2;
  unsigned short* enc  = (unsigned short*)(w + off); off += (size_t)65536 * 128 * 2;
  unsigned short* kbuf = (unsigned short*)(w + off); off += (size_t)65536 * 128 * 2;
  unsigned short* vbuf = (unsigned short*)(w + off); off += (size_t)65536 * 128 * 2;
  unsigned* w0t  = (unsigned*)(w + off); off += (size_t)68 * 512 * 4;
  unsigned* wh0t = (unsigned*)(w + off); off += (size_t)64 * 512 * 4;
  unsigned* wi1t = (unsigned*)(w + off); off += (size_t)64 * 512 * 4;
  unsigned* wh1t = (unsigned*)(w + off); off += (size_t)64 * 512 * 4;
  unsigned* wqt  = (unsigned*)(w + off); off += (size_t)64 * 128 * 4;
  unsigned* wot  = (unsigned*)(w + off); off += (size_t)64 * 128 * 4;
  float* lwcWo   = (float*)(w + off);    off += 4 * 128 * 4;
  float* linb2   = (float*)(w + off);    off += 64;
  unsigned short* xbf = (unsigned short*)(w + off);
  const size_t need_big = off + (size_t)65536 * 1024 * 2;
  const bool big = ws_size >= need_big;

  // decoder weight packing (R13-identical)
  packTg<<<(68 * 512 + 255) / 256, 256, 0, stream>>>(dWih0, w0t, 132, 68);
  packTg<<<(64 * 512 + 255) / 256, 256, 0, stream>>>(dWhh0, wh0t, 128, 64);
  packTg<<<(64 * 512 + 255) / 256, 256, 0, stream>>>(dWih1, wi1t, 128, 64);
  packTg<<<(64 * 512 + 255) / 256, 256, 0, stream>>>(dWhh1, wh1t, 128, 64);
  packT<<<(64 * 128 + 255) / 256, 256, 0, stream>>>(Wq, wqt, 128, 128, 64);
  packT<<<(64 * 128 + 255) / 256, 256, 0, stream>>>(Wo, wot, 128, 128, 64);
  foldWo<<<1, 512, 0, stream>>>(linW, Wo, bo, linb, lwcWo, linb2);

  // encoder
  if (big) {
    f2bf_vec<<<65536, 256, 0, stream>>>(x, xbf);
    gemm_bt<1, 0><<<dim3(4, 512), 256, 0, stream>>>((const void*)xbf, eWih0, eb0, (void*)pre, 65536, 512, 1024);
  } else {
    gemm_bt<0, 0><<<dim3(4, 512), 256, 0, stream>>>((const void*)x, eWih0, eb0, (void*)pre, 65536, 512, 1024);
  }
  lstm_scan<0><<<8, 512, 0, stream>>>((const void*)pre, eWhh0, hs0, 512);
  // layer-1 pre in bf16 (halves gemm2 write + scan1 read traffic)
  gemm_bt<1, 1><<<dim3(4, 512), 256, 0, stream>>>((const void*)hs0, eWih1, eb1, (void*)pre, 65536, 512, 128);
  lstm_scan<1><<<8, 512, 0, stream>>>((const void*)pre, eWhh1, enc, 512);
  // K/V projections
  gemm_bt<1, 1><<<dim3(1, 512), 256, 0, stream>>>((const void*)enc, Wk, bk, (void*)kbuf, 65536, 128, 128);
  gemm_bt<1, 1><<<dim3(1, 512), 256, 0, stream>>>((const void*)enc, Wv, bv, (void*)vbuf, 65536, 128, 128);

  // self-contained decoder: 128 WGs, one per batch, 6 phases/step
  hipFuncSetAttribute((const void*)decoder_single,
                      hipFuncAttributeMaxDynamicSharedMemorySize, DEC_SMEM);
  decoder_single<<<128, 512, DEC_SMEM, stream>>>(kbuf, vbuf, w0t, wh0t, wi1t, wh1t, wqt, wot,
      db0, db1, bq, bo, linW, lwcWo, linb2, (float*)d_out);
}